// Round 6
// baseline (4681.953 us; speedup 1.0000x reference)
//
#include <hip/hip_runtime.h>

typedef _Float16 h2_t __attribute__((ext_vector_type(2)));
typedef _Float16 h8_t __attribute__((ext_vector_type(8)));
typedef float    f4_t __attribute__((ext_vector_type(4)));
typedef unsigned short u16;

#define EMB   512
#define VOCAB 256
#define NB    64
#define NT    1024

__device__ __forceinline__ float fast_tanh(float z) {
    float e = __expf(2.0f * z);
    return 1.0f - 2.0f / (e + 1.0f);
}

__device__ __forceinline__ unsigned pk2(float a, float b) {
    return __builtin_bit_cast(unsigned, __builtin_amdgcn_cvt_pkrtz(a, b));
}

// ---------------------------------------------------------------------------
// Prep: emb_proj = emb @ w_x^T + b_cell (f32); pack w_h -> f16 (row-major W2);
// pack w_head -> f16; pack streamed w_h slabs 9..15 into MFMA-frag order Wstr.
// ---------------------------------------------------------------------------
__global__ __launch_bounds__(256) void prep_kernel(
    const float* __restrict__ emb, const float* __restrict__ w_cell,
    const float* __restrict__ b_cell, const float* __restrict__ w_head,
    float* __restrict__ embp, unsigned* __restrict__ W2, u16* __restrict__ wh16,
    u16* __restrict__ Wstr)
{
    const int blk = blockIdx.x, tid = threadIdx.x;
    if (blk < 256) {
        const int v = blk;
        __shared__ __align__(16) float er[EMB];
        er[tid]       = emb[v * EMB + tid];
        er[tid + 256] = emb[v * EMB + 256 + tid];
        __syncthreads();
        const f4_t* er4 = (const f4_t*)er;
        #pragma unroll
        for (int half = 0; half < 2; ++half) {
            const int o = tid + half * 256;
            const f4_t* wr4 = (const f4_t*)(w_cell + (size_t)o * 1024); // w_x row o
            float s0 = 0.f, s1 = 0.f, s2 = 0.f, s3 = 0.f;
            #pragma unroll 8
            for (int e4 = 0; e4 < 128; ++e4) {
                f4_t w = wr4[e4], a = er4[e4];
                s0 = fmaf(w[0], a[0], s0);
                s1 = fmaf(w[1], a[1], s1);
                s2 = fmaf(w[2], a[2], s2);
                s3 = fmaf(w[3], a[3], s3);
            }
            embp[v * EMB + o] = (s0 + s1) + (s2 + s3) + b_cell[o];
        }
    } else if (blk < 384) {
        // pack w_h[o][e] (= w_cell[o*1024 + 512 + e]) into f16: W2 as u16[o*512+e]
        const int base = (blk - 256) * 1024 + tid;
        #pragma unroll
        for (int i = 0; i < 4; ++i) {
            const int P = base + i * 256;          // 0..131071 (pairs)
            const int o = P >> 8, p = P & 255;
            h2_t v2;
            v2[0] = (_Float16)w_cell[(size_t)o * 1024 + 512 + 2 * p];
            v2[1] = (_Float16)w_cell[(size_t)o * 1024 + 512 + 2 * p + 1];
            W2[P] = __builtin_bit_cast(unsigned, v2);
        }
    } else if (blk < 448) {
        const int base = (blk - 384) * 2048 + tid;
        #pragma unroll
        for (int i = 0; i < 8; ++i) {
            const int idx = base + i * 256;        // 0..131071
            wh16[idx] = __builtin_bit_cast(u16, (_Float16)w_head[idx]);
        }
    } else {
        // streamed A-fragments, slabs 9..15: frag f=(sp*32+I)*64+lane holds
        // w_h[m = I*16 + (lane&15)][k = (9+sp)*32 + (lane>>4)*8 .. +7] as f16 x8
        const int f  = (blk - 448) * 256 + tid;    // 0..14335
        const int sp = f >> 11, I = (f >> 6) & 31, ln = f & 63;
        const int m  = I * 16 + (ln & 15);
        const int k  = (9 + sp) * 32 + ((ln >> 4) << 3);
        const float* src = w_cell + (size_t)m * 1024 + 512 + k;
        u16 tmp[8];
        #pragma unroll
        for (int j = 0; j < 8; ++j)
            tmp[j] = __builtin_bit_cast(u16, (_Float16)src[j]);
        *(uint4*)&Wstr[(size_t)f * 8] = *(const uint4*)tmp;
    }
}

// ---------------------------------------------------------------------------
// Recurrence, transposed MFMA: h_new^T[512 x 16] = w_h x h^T per step.
// 4 blocks x 512 threads (2 waves/SIMD; combined VGPR+AGPR budget 256/lane).
// w_h sourcing (512 KB can't fully fit the 512 KB/CU register file):
//   slabs 0..8  (288 KB): AGPR-resident, Af[4][9] = 144 regs/lane.
//   slabs 9..15 (224 KB): STREAMED from L2 each step via 2 rotating uint4[4]
//   buffers (global loads: per-wave private -> no barrier coupling, vmcnt
//   only; reloads interleaved with MFMAs; next step's first 2 slabs load
//   during the epilogue). zo (=0, from token) defeats LICM of the
//   loop-invariant addresses.
// h double-buffered in LDS, MFMA-B-frag order -> stride-1 ds_read_b128.
// Barrier = raw lgkmcnt-only s_barrier (no vmcnt drain). xw gather is the
// MFMA C-init, loaded one step ahead; hs stores fire-and-forget.
// ---------------------------------------------------------------------------
__global__ __launch_bounds__(512, 2) void rnn_rec(
    const int* __restrict__ x, const float* __restrict__ h0,
    const u16* __restrict__ whf, const float* __restrict__ embp,
    const uint4* __restrict__ Wp, u16* __restrict__ hs)
{
    const int tid  = threadIdx.x;
    const int wave = tid >> 6, lane = tid & 63;
    const int n    = lane & 15, quad = lane >> 4;   // n = batch-in-block
    const int b0   = blockIdx.x * 16;

    __shared__ __align__(16) u16 hbuf[2][8192];     // B-frag order, 2 x 16 KB

    {   // h0 -> buffer 0, all 16 batch columns (B-frag order)
        const u16 u = __builtin_bit_cast(u16, (_Float16)h0[tid]);
        const int e = tid;
        const int ob = ((e >> 5) * 64 + ((e >> 3) & 3) * 16) * 8 + (e & 7);
        #pragma unroll
        for (int nn = 0; nn < 16; ++nn) hbuf[0][ob + nn * 8] = u;
    }

    // ---- resident A fragments: rows m = (wave*4+i)*16+n, k-slabs 0..8 ----
    h8_t Af[4][9];
    #pragma unroll
    for (int i = 0; i < 4; ++i)
        #pragma unroll
        for (int s = 0; s < 9; ++s)
            Af[i][s] = *(const h8_t*)&whf[(size_t)(((wave << 2) + i) * 16 + n) * EMB
                                          + s * 32 + quad * 8];

    const int* xp  = x  + (size_t)(b0 + n) * NT;
    u16*       hsp = hs + (size_t)(b0 + n) * NT * EMB;

    int eofs[4], wofs[4];
    #pragma unroll
    for (int i = 0; i < 4; ++i) {
        const int I = (wave << 2) + i;
        eofs[i] = I * 16 + (quad << 2);                       // e-offset of acc[i]
        const int qq = (2 * I + (quad >> 1)) & 3;
        wofs[i] = ((I >> 1) * 64 + qq * 16 + n) * 8 + (quad & 1) * 4;
    }

#define STR_LOAD(BUF, SP)                                                    \
    _Pragma("unroll")                                                        \
    for (int i_ = 0; i_ < 4; ++i_)                                           \
        BUF[i_] = Wp[(size_t)(((SP) * 32 + ((wave << 2) + i_)) * 64 + lane + zo)];

#define STR_MFMA(BUF, S)                                                     \
    {   const h8_t bf_ = *(const h8_t*)&hb[(S) * 512 + lane * 8];            \
        _Pragma("unroll")                                                    \
        for (int i_ = 0; i_ < 4; ++i_)                                       \
            acc[i_] = __builtin_amdgcn_mfma_f32_16x16x32_f16(                \
                __builtin_bit_cast(h8_t, BUF[i_]), bf_, acc[i_], 0, 0, 0); }

#define RES_MFMA(S)                                                          \
    {   const h8_t bf_ = *(const h8_t*)&hb[(S) * 512 + lane * 8];            \
        _Pragma("unroll")                                                    \
        for (int i_ = 0; i_ < 4; ++i_)                                       \
            acc[i_] = __builtin_amdgcn_mfma_f32_16x16x32_f16(                \
                Af[i_][S], bf_, acc[i_], 0, 0, 0); }

    int vcur = xp[0];                       // token t (carried)
    int zo   = vcur >> 20;                  // always 0; defeats LICM
    uint4 sb0[4], sb1[4];
    STR_LOAD(sb0, 0);                       // slab 9
    STR_LOAD(sb1, 1);                       // slab 10
    f4_t xw[4];
    #pragma unroll
    for (int i = 0; i < 4; ++i)
        xw[i] = *(const f4_t*)&embp[(size_t)vcur * EMB + eofs[i]];
    int vB = xp[1];                         // token t+1

    __syncthreads();

    #pragma unroll 1
    for (int t = 0; t < NT; ++t) {
        zo = vcur >> 20;
        const u16* hb = &hbuf[t & 1][0];
        f4_t acc[4];
        #pragma unroll
        for (int i = 0; i < 4; ++i) acc[i] = xw[i];           // xw as C-init

        // MFMA phase; streamed-buffer reloads interleaved for latency cover
        STR_MFMA(sb0, 9);   STR_LOAD(sb0, 2);                 // -> slab 11
        RES_MFMA(0); RES_MFMA(1); RES_MFMA(2);
        STR_MFMA(sb1, 10);  STR_LOAD(sb1, 3);                 // -> slab 12
        RES_MFMA(3); RES_MFMA(4); RES_MFMA(5);
        STR_MFMA(sb0, 11);  STR_LOAD(sb0, 4);                 // -> slab 13
        RES_MFMA(6); RES_MFMA(7); RES_MFMA(8);
        STR_MFMA(sb1, 12);  STR_LOAD(sb1, 5);                 // -> slab 14
        STR_MFMA(sb0, 13);  STR_LOAD(sb0, 6);                 // -> slab 15
        STR_MFMA(sb1, 14);  STR_LOAD(sb1, 1);                 // -> slab 10, t+1
        STR_MFMA(sb0, 15);  STR_LOAD(sb0, 0);                 // -> slab 9,  t+1

        // epilogue: tanh -> f16, LDS (B-frag order) + global hs
        u16* hw = &hbuf[(t + 1) & 1][0];
        #pragma unroll
        for (int i = 0; i < 4; ++i) {
            const f4_t a = acc[i];
            uint2 pk;
            pk.x = pk2(fast_tanh(a[0]), fast_tanh(a[1]));
            pk.y = pk2(fast_tanh(a[2]), fast_tanh(a[3]));
            *(uint2*)&hw[wofs[i]] = pk;
            *(uint2*)&hsp[(size_t)t * EMB + eofs[i]] = pk;    // no drain
        }

        // next step's xw (C-init) and token
        #pragma unroll
        for (int i = 0; i < 4; ++i)
            xw[i] = *(const f4_t*)&embp[(size_t)vB * EMB + eofs[i]];
        vcur = vB;
        vB = xp[(t + 2 < NT) ? t + 2 : NT - 1];

        // LDS-only barrier: NO vmcnt drain (hs stores / gathers / streams fly)
        asm volatile("s_waitcnt lgkmcnt(0)\n\ts_barrier" ::: "memory");
    }
#undef STR_LOAD
#undef STR_MFMA
#undef RES_MFMA
}

// ---------------------------------------------------------------------------
// Head: out[bt][n] = hs[bt][:] @ w_head[n][:]^T + b_head[n], MFMA f16 16x16x32.
// ---------------------------------------------------------------------------
__global__ __launch_bounds__(512, 2) void head_kernel(
    const u16* __restrict__ hs, const u16* __restrict__ wh16,
    const float* __restrict__ b_head, float* __restrict__ out)
{
    const int tid  = threadIdx.x;
    const int wave = tid >> 6, lane = tid & 63;
    const int l15  = lane & 15, q = lane >> 4;
    const int bt0  = blockIdx.x * 64;

    __shared__ __align__(16) u16 As[64][520];   // +8 halfs pad: breaks bank aliasing

    {   // stage 64x512 f16 tile
        const uint4* src = (const uint4*)(hs + (size_t)bt0 * EMB);
        #pragma unroll
        for (int i = 0; i < 8; ++i) {
            const int idx = tid + i * 512;       // 0..4095 uint4s
            const int row = idx >> 6, col8 = idx & 63;
            *(uint4*)&As[row][col8 * 8] = src[idx];
        }
    }

    // B fragments: wave owns n-tiles {2*wave, 2*wave+1}; B[k][n] = w_head[n][k]
    uint4 bn[16][2];
    #pragma unroll
    for (int i = 0; i < 16; ++i)
        #pragma unroll
        for (int j = 0; j < 2; ++j) {
            const int n = wave * 32 + j * 16 + l15;
            const int k = i * 32 + q * 8;
            bn[i][j] = *(const uint4*)(wh16 + (size_t)n * EMB + k);
        }
    __syncthreads();

    #pragma unroll 1
    for (int mt = 0; mt < 4; ++mt) {
        f4_t acc0 = {0.f, 0.f, 0.f, 0.f}, acc1 = {0.f, 0.f, 0.f, 0.f};
        const int row = mt * 16 + l15;
        #pragma unroll
        for (int i = 0; i < 16; ++i) {
            const int k = i * 32 + q * 8;
            h8_t a = *(const h8_t*)&As[row][k];
            acc0 = __builtin_amdgcn_mfma_f32_16x16x32_f16(
                a, __builtin_bit_cast(h8_t, bn[i][0]), acc0, 0, 0, 0);
            acc1 = __builtin_amdgcn_mfma_f32_16x16x32_f16(
                a, __builtin_bit_cast(h8_t, bn[i][1]), acc1, 0, 0, 0);
        }
        #pragma unroll
        for (int j = 0; j < 2; ++j) {
            const int n = wave * 32 + j * 16 + l15;
            const float bh = b_head[n];
            const f4_t av = j ? acc1 : acc0;
            #pragma unroll
            for (int r = 0; r < 4; ++r) {
                const int orow = bt0 + mt * 16 + q * 4 + r;   // D: row=q*4+r, col=l15
                out[(size_t)orow * VOCAB + n] = av[r] + bh;
            }
        }
    }
}

extern "C" void kernel_launch(void* const* d_in, const int* in_sizes, int n_in,
                              void* d_out, int out_size, void* d_ws, size_t ws_size,
                              hipStream_t stream) {
    (void)in_sizes; (void)n_in; (void)out_size; (void)ws_size;
    const int*   x      = (const int*)  d_in[0];
    const float* emb    = (const float*)d_in[1];
    const float* w_cell = (const float*)d_in[2];
    const float* b_cell = (const float*)d_in[3];
    const float* w_head = (const float*)d_in[4];
    const float* b_head = (const float*)d_in[5];
    const float* h0     = (const float*)d_in[6];
    float* out = (float*)d_out;

    char* ws = (char*)d_ws;
    float*    embp = (float*)   (ws);                 // 256*512*4 = 512 KB
    unsigned* W2   = (unsigned*)(ws + 524288);        // 512*256*4 = 512 KB (f16 w_h)
    u16*      wh16 = (u16*)     (ws + 1048576);       // 256*512*2 = 256 KB
    u16*      Wstr = (u16*)     (ws + 1310720);       // 7*32*64*16 = 224 KB
    u16*      hs   = (u16*)     (ws + 1540096);       // 64*1024*512*2 = 64 MB

    prep_kernel<<<dim3(504), dim3(256), 0, stream>>>(emb, w_cell, b_cell, w_head,
                                                     embp, W2, wh16, Wstr);
    rnn_rec<<<dim3(4), dim3(512), 0, stream>>>(x, h0, (const u16*)W2, embp,
                                               (const uint4*)Wstr, hs);
    head_kernel<<<dim3((NB * NT) / 64), dim3(512), 0, stream>>>(hs, wh16, b_head, out);
}